// Round 1
// baseline (3091.235 us; speedup 1.0000x reference)
//
#include <hip/hip_runtime.h>

#define NN 100000
#define NE 1600000
#define DD 128
#define BN_EPS 1e-5f

// ---------------------------------------------------------------------------
// Kernel 1: acc = (1+eps)*h   (also zero the BN stats buffer)
// ---------------------------------------------------------------------------
__global__ __launch_bounds__(256) void init_acc_kernel(
    const float* __restrict__ h, const float* __restrict__ eps,
    float* __restrict__ acc, float* __restrict__ stats)
{
    const float s = 1.0f + eps[0];
    const float4* h4 = (const float4*)h;
    float4* a4 = (float4*)acc;
    const int total = NN * (DD / 4);
    for (int i = blockIdx.x * blockDim.x + threadIdx.x; i < total;
         i += gridDim.x * blockDim.x) {
        float4 v = h4[i];
        v.x *= s; v.y *= s; v.z *= s; v.w *= s;
        a4[i] = v;
    }
    if (blockIdx.x == 0 && threadIdx.x < 2 * DD) stats[threadIdx.x] = 0.0f;
}

// ---------------------------------------------------------------------------
// Kernel 2: acc[dst[e], :] += h[src[e], :]  (32 threads/edge, float4 each)
// ---------------------------------------------------------------------------
__global__ __launch_bounds__(256) void scatter_kernel(
    const float* __restrict__ h, const int* __restrict__ src,
    const int* __restrict__ dst, float* __restrict__ acc)
{
    int idx = blockIdx.x * blockDim.x + threadIdx.x;
    if (idx >= NE * 32) return;
    int e  = idx >> 5;
    int c4 = idx & 31;
    int s = src[e];
    int d = dst[e];
    float4 v = ((const float4*)h)[s * 32 + c4];
    float* ap = acc + (long long)d * DD + (c4 << 2);
    atomicAdd(ap + 0, v.x);
    atomicAdd(ap + 1, v.y);
    atomicAdd(ap + 2, v.z);
    atomicAdd(ap + 3, v.w);
}

// ---------------------------------------------------------------------------
// Kernel 3: Y = (relu?)(X @ W + b)  for D=128. Block = 64 rows x 128 cols,
// 256 threads. Thread (rg=tid>>5, cg=tid&31) computes rows rg+8*i (i<8),
// cols cg*4..cg*4+3. K chunked by 32. In-place safe (block reads only its
// own rows; all global reads precede its writes).
// ---------------------------------------------------------------------------
template <bool RELU>
__global__ __launch_bounds__(256) void gemm128_kernel(
    const float* __restrict__ X, const float* __restrict__ W,
    const float* __restrict__ bias, float* __restrict__ Y, int n)
{
    __shared__ float xs[64][32];    // 8 KB
    __shared__ float wsm[32][128];  // 16 KB

    const int tid = threadIdx.x;
    const int cg = tid & 31;
    const int rg = tid >> 5;
    const int r0 = blockIdx.x * 64;

    const float4* X4 = (const float4*)X;
    const float4* W4 = (const float4*)W;
    float4* Y4 = (float4*)Y;

    float4 acc[8];
#pragma unroll
    for (int i = 0; i < 8; ++i) acc[i] = make_float4(0.f, 0.f, 0.f, 0.f);

    for (int kb = 0; kb < 4; ++kb) {
        // stage X chunk: 64 rows x 32 k = 512 float4
#pragma unroll
        for (int l = 0; l < 2; ++l) {
            int j = tid + l * 256;
            int row = j >> 3;
            int kc = j & 7;
            int grow = r0 + row;
            float4 v = make_float4(0.f, 0.f, 0.f, 0.f);
            if (grow < n) v = X4[grow * 32 + kb * 8 + kc];
            *(float4*)&xs[row][kc << 2] = v;
        }
        // stage W chunk: 32 k x 128 cols = 1024 float4
#pragma unroll
        for (int l = 0; l < 4; ++l) {
            int j = tid + l * 256;
            int kr = j >> 5;
            int kc = j & 31;
            *(float4*)&wsm[kr][kc << 2] = W4[(kb * 32 + kr) * 32 + kc];
        }
        __syncthreads();

#pragma unroll
        for (int k4 = 0; k4 < 8; ++k4) {
            float4 w0 = *(const float4*)&wsm[k4 * 4 + 0][cg << 2];
            float4 w1 = *(const float4*)&wsm[k4 * 4 + 1][cg << 2];
            float4 w2 = *(const float4*)&wsm[k4 * 4 + 2][cg << 2];
            float4 w3 = *(const float4*)&wsm[k4 * 4 + 3][cg << 2];
#pragma unroll
            for (int i = 0; i < 8; ++i) {
                float4 xv = *(const float4*)&xs[rg + 8 * i][k4 << 2];
                acc[i].x += xv.x * w0.x + xv.y * w1.x + xv.z * w2.x + xv.w * w3.x;
                acc[i].y += xv.x * w0.y + xv.y * w1.y + xv.z * w2.y + xv.w * w3.y;
                acc[i].z += xv.x * w0.z + xv.y * w1.z + xv.z * w2.z + xv.w * w3.z;
                acc[i].w += xv.x * w0.w + xv.y * w1.w + xv.z * w2.w + xv.w * w3.w;
            }
        }
        __syncthreads();
    }

    float4 bv = ((const float4*)bias)[cg];
#pragma unroll
    for (int i = 0; i < 8; ++i) {
        int grow = r0 + rg + 8 * i;
        if (grow < n) {
            float4 r;
            r.x = acc[i].x + bv.x;
            r.y = acc[i].y + bv.y;
            r.z = acc[i].z + bv.z;
            r.w = acc[i].w + bv.w;
            if (RELU) {
                r.x = fmaxf(r.x, 0.f);
                r.y = fmaxf(r.y, 0.f);
                r.z = fmaxf(r.z, 0.f);
                r.w = fmaxf(r.w, 0.f);
            }
            Y4[grow * 32 + cg] = r;
        }
    }
}

// ---------------------------------------------------------------------------
// Kernel 4: per-column sum & sumsq of Y [N,128] -> stats[0:128]=sum,
// stats[128:256]=sumsq
// ---------------------------------------------------------------------------
__global__ __launch_bounds__(256) void bn_stats_kernel(
    const float* __restrict__ Y, float* __restrict__ stats)
{
    const int cg = threadIdx.x & 31;
    const int rg = threadIdx.x >> 5;
    const float4* Y4 = (const float4*)Y;

    float4 s = make_float4(0.f, 0.f, 0.f, 0.f);
    float4 q = make_float4(0.f, 0.f, 0.f, 0.f);
    for (int r = blockIdx.x * 8 + rg; r < NN; r += gridDim.x * 8) {
        float4 v = Y4[r * 32 + cg];
        s.x += v.x; s.y += v.y; s.z += v.z; s.w += v.w;
        q.x += v.x * v.x; q.y += v.y * v.y; q.z += v.z * v.z; q.w += v.w * v.w;
    }

    __shared__ float4 ls[8][32];
    __shared__ float4 lq[8][32];
    ls[rg][cg] = s;
    lq[rg][cg] = q;
    __syncthreads();
    if (rg == 0) {
        float4 ts = ls[0][cg], tq = lq[0][cg];
#pragma unroll
        for (int i = 1; i < 8; ++i) {
            float4 a = ls[i][cg], b = lq[i][cg];
            ts.x += a.x; ts.y += a.y; ts.z += a.z; ts.w += a.w;
            tq.x += b.x; tq.y += b.y; tq.z += b.z; tq.w += b.w;
        }
        int c = cg << 2;
        atomicAdd(&stats[c + 0], ts.x);
        atomicAdd(&stats[c + 1], ts.y);
        atomicAdd(&stats[c + 2], ts.z);
        atomicAdd(&stats[c + 3], ts.w);
        atomicAdd(&stats[DD + c + 0], tq.x);
        atomicAdd(&stats[DD + c + 1], tq.y);
        atomicAdd(&stats[DD + c + 2], tq.z);
        atomicAdd(&stats[DD + c + 3], tq.w);
    }
}

// ---------------------------------------------------------------------------
// Kernel 5: out = h + relu((Y - mean) * rsqrt(var+eps) * gamma + beta)
// ---------------------------------------------------------------------------
__global__ __launch_bounds__(256) void bn_final_kernel(
    const float* __restrict__ Y, const float* __restrict__ h,
    const float* __restrict__ gamma, const float* __restrict__ beta,
    const float* __restrict__ stats, float* __restrict__ out)
{
    const float invN = 1.0f / (float)NN;
    const float4* Y4 = (const float4*)Y;
    const float4* H4 = (const float4*)h;
    float4* O4 = (float4*)out;
    const int total = NN * (DD / 4);
    for (int i = blockIdx.x * blockDim.x + threadIdx.x; i < total;
         i += gridDim.x * blockDim.x) {
        int cg = i & 31;
        int c = cg << 2;
        float4 v = Y4[i];
        float4 hv = H4[i];
        float4 g = ((const float4*)gamma)[cg];
        float4 bt = ((const float4*)beta)[cg];

        float m0 = stats[c + 0] * invN, m1 = stats[c + 1] * invN;
        float m2 = stats[c + 2] * invN, m3 = stats[c + 3] * invN;
        float v0 = stats[DD + c + 0] * invN - m0 * m0;
        float v1 = stats[DD + c + 1] * invN - m1 * m1;
        float v2 = stats[DD + c + 2] * invN - m2 * m2;
        float v3 = stats[DD + c + 3] * invN - m3 * m3;

        float4 r;
        r.x = hv.x + fmaxf((v.x - m0) * rsqrtf(v0 + BN_EPS) * g.x + bt.x, 0.f);
        r.y = hv.y + fmaxf((v.y - m1) * rsqrtf(v1 + BN_EPS) * g.y + bt.y, 0.f);
        r.z = hv.z + fmaxf((v.z - m2) * rsqrtf(v2 + BN_EPS) * g.z + bt.z, 0.f);
        r.w = hv.w + fmaxf((v.w - m3) * rsqrtf(v3 + BN_EPS) * g.w + bt.w, 0.f);
        O4[i] = r;
    }
}

// ---------------------------------------------------------------------------
extern "C" void kernel_launch(void* const* d_in, const int* in_sizes, int n_in,
                              void* d_out, int out_size, void* d_ws, size_t ws_size,
                              hipStream_t stream)
{
    const float* h     = (const float*)d_in[0];
    const int*   src   = (const int*)d_in[1];
    const int*   dst   = (const int*)d_in[2];
    const float* eps   = (const float*)d_in[3];
    const float* W1    = (const float*)d_in[4];
    const float* b1    = (const float*)d_in[5];
    const float* W2    = (const float*)d_in[6];
    const float* b2    = (const float*)d_in[7];
    const float* gamma = (const float*)d_in[8];
    const float* beta  = (const float*)d_in[9];
    float* out = (float*)d_out;

    float* acc   = (float*)d_ws;                 // NN*DD floats (51.2 MB)
    float* stats = acc + (size_t)NN * DD;        // 256 floats

    // 1. acc = (1+eps)*h ; zero stats
    init_acc_kernel<<<1024, 256, 0, stream>>>(h, eps, acc, stats);

    // 2. scatter-add neighbor messages
    int scatter_blocks = (NE * 32 + 255) / 256;  // 200000
    scatter_kernel<<<scatter_blocks, 256, 0, stream>>>(h, src, dst, acc);

    // 3. acc = relu(acc @ W1 + b1)   (in-place)
    int gemm_blocks = (NN + 63) / 64;            // 1563
    gemm128_kernel<true><<<gemm_blocks, 256, 0, stream>>>(acc, W1, b1, acc, NN);

    // 4. out = acc @ W2 + b2
    gemm128_kernel<false><<<gemm_blocks, 256, 0, stream>>>(acc, W2, b2, out, NN);

    // 5. BN stats over out
    bn_stats_kernel<<<512, 256, 0, stream>>>(out, stats);

    // 6. out = h + relu(BN(out))   (in-place)
    bn_final_kernel<<<1024, 256, 0, stream>>>(out, h, gamma, beta, stats, out);
}

// Round 2
// 952.712 us; speedup vs baseline: 3.2447x; 3.2447x over previous
//
#include <hip/hip_runtime.h>

#define NN 100000
#define NE 1600000
#define DD 128
#define BN_EPS 1e-5f

// ---------------------------------------------------------------------------
// Kernel 0: zero deg[] and stats[]
// ---------------------------------------------------------------------------
__global__ __launch_bounds__(256) void zero_kernel(
    int* __restrict__ deg, float* __restrict__ stats)
{
    for (int i = blockIdx.x * blockDim.x + threadIdx.x; i < NN;
         i += gridDim.x * blockDim.x)
        deg[i] = 0;
    if (blockIdx.x == 0 && threadIdx.x < 2 * DD) stats[threadIdx.x] = 0.0f;
}

// ---------------------------------------------------------------------------
// Kernel 1: histogram of dst
// ---------------------------------------------------------------------------
__global__ __launch_bounds__(256) void hist_kernel(
    const int* __restrict__ dst, int* __restrict__ deg)
{
    int e = blockIdx.x * blockDim.x + threadIdx.x;
    if (e < NE) atomicAdd(&deg[dst[e]], 1);
}

// ---------------------------------------------------------------------------
// Kernel 2: single-block exclusive scan deg -> off (and cursor copy).
// 1024 threads, 98 contiguous elements each.
// ---------------------------------------------------------------------------
__global__ __launch_bounds__(1024) void scan_kernel(
    const int* __restrict__ deg, int* __restrict__ off, int* __restrict__ cursor)
{
    const int CH = 98;  // 1024*98 = 100352 >= NN
    __shared__ int part[1024];
    int t = threadIdx.x;
    int base = t * CH;
    int sum = 0;
    for (int i = 0; i < CH; ++i) {
        int j = base + i;
        if (j < NN) sum += deg[j];
    }
    part[t] = sum;
    __syncthreads();
    // Hillis-Steele inclusive scan
    for (int ofs = 1; ofs < 1024; ofs <<= 1) {
        int v = (t >= ofs) ? part[t - ofs] : 0;
        __syncthreads();
        part[t] += v;
        __syncthreads();
    }
    int run = part[t] - sum;  // exclusive prefix of this chunk
    for (int i = 0; i < CH; ++i) {
        int j = base + i;
        if (j < NN) {
            off[j] = run;
            cursor[j] = run;
            run += deg[j];
        }
    }
    if (t == 1023) off[NN] = run;  // == NE
}

// ---------------------------------------------------------------------------
// Kernel 3: bucket-scatter edge sources into CSR order
// ---------------------------------------------------------------------------
__global__ __launch_bounds__(256) void sort_edges_kernel(
    const int* __restrict__ src, const int* __restrict__ dst,
    int* __restrict__ cursor, int* __restrict__ src_sorted)
{
    int e = blockIdx.x * blockDim.x + threadIdx.x;
    if (e < NE) {
        int pos = atomicAdd(&cursor[dst[e]], 1);
        src_sorted[pos] = src[e];
    }
}

// ---------------------------------------------------------------------------
// Kernel 4: out[n,:] = (1+eps)*h[n,:] + sum_{e in CSR[n]} h[src_sorted[e],:]
// 32 threads per node (float4 each), 8 nodes per 256-thread block.
// ---------------------------------------------------------------------------
__global__ __launch_bounds__(256) void gather_sum_kernel(
    const float* __restrict__ h, const float* __restrict__ eps,
    const int* __restrict__ off, const int* __restrict__ src_sorted,
    float* __restrict__ out)
{
    int node = blockIdx.x * 8 + (threadIdx.x >> 5);
    if (node >= NN) return;
    int c4 = threadIdx.x & 31;
    const float4* h4 = (const float4*)h;

    const float s = 1.0f + eps[0];
    float4 a = h4[node * 32 + c4];
    a.x *= s; a.y *= s; a.z *= s; a.w *= s;

    int e = off[node];
    int eend = off[node + 1];
    for (; e + 1 < eend; e += 2) {
        int s0 = src_sorted[e];
        int s1 = src_sorted[e + 1];
        float4 v0 = h4[s0 * 32 + c4];
        float4 v1 = h4[s1 * 32 + c4];
        a.x += v0.x + v1.x;
        a.y += v0.y + v1.y;
        a.z += v0.z + v1.z;
        a.w += v0.w + v1.w;
    }
    if (e < eend) {
        int s0 = src_sorted[e];
        float4 v0 = h4[s0 * 32 + c4];
        a.x += v0.x; a.y += v0.y; a.z += v0.z; a.w += v0.w;
    }
    ((float4*)out)[node * 32 + c4] = a;
}

// ---------------------------------------------------------------------------
// Kernel 5: Y = (relu?)(X @ W + b)  for D=128. Block = 64 rows x 128 cols,
// 256 threads. In-place safe (block reads only its own rows; all global
// reads precede its writes).
// ---------------------------------------------------------------------------
template <bool RELU>
__global__ __launch_bounds__(256) void gemm128_kernel(
    const float* __restrict__ X, const float* __restrict__ W,
    const float* __restrict__ bias, float* __restrict__ Y, int n)
{
    __shared__ float xs[64][32];    // 8 KB
    __shared__ float wsm[32][128];  // 16 KB

    const int tid = threadIdx.x;
    const int cg = tid & 31;
    const int rg = tid >> 5;
    const int r0 = blockIdx.x * 64;

    const float4* X4 = (const float4*)X;
    const float4* W4 = (const float4*)W;
    float4* Y4 = (float4*)Y;

    float4 acc[8];
#pragma unroll
    for (int i = 0; i < 8; ++i) acc[i] = make_float4(0.f, 0.f, 0.f, 0.f);

    for (int kb = 0; kb < 4; ++kb) {
#pragma unroll
        for (int l = 0; l < 2; ++l) {
            int j = tid + l * 256;
            int row = j >> 3;
            int kc = j & 7;
            int grow = r0 + row;
            float4 v = make_float4(0.f, 0.f, 0.f, 0.f);
            if (grow < n) v = X4[grow * 32 + kb * 8 + kc];
            *(float4*)&xs[row][kc << 2] = v;
        }
#pragma unroll
        for (int l = 0; l < 4; ++l) {
            int j = tid + l * 256;
            int kr = j >> 5;
            int kc = j & 31;
            *(float4*)&wsm[kr][kc << 2] = W4[(kb * 32 + kr) * 32 + kc];
        }
        __syncthreads();

#pragma unroll
        for (int k4 = 0; k4 < 8; ++k4) {
            float4 w0 = *(const float4*)&wsm[k4 * 4 + 0][cg << 2];
            float4 w1 = *(const float4*)&wsm[k4 * 4 + 1][cg << 2];
            float4 w2 = *(const float4*)&wsm[k4 * 4 + 2][cg << 2];
            float4 w3 = *(const float4*)&wsm[k4 * 4 + 3][cg << 2];
#pragma unroll
            for (int i = 0; i < 8; ++i) {
                float4 xv = *(const float4*)&xs[rg + 8 * i][k4 << 2];
                acc[i].x += xv.x * w0.x + xv.y * w1.x + xv.z * w2.x + xv.w * w3.x;
                acc[i].y += xv.x * w0.y + xv.y * w1.y + xv.z * w2.y + xv.w * w3.y;
                acc[i].z += xv.x * w0.z + xv.y * w1.z + xv.z * w2.z + xv.w * w3.z;
                acc[i].w += xv.x * w0.w + xv.y * w1.w + xv.z * w2.w + xv.w * w3.w;
            }
        }
        __syncthreads();
    }

    float4 bv = ((const float4*)bias)[cg];
#pragma unroll
    for (int i = 0; i < 8; ++i) {
        int grow = r0 + rg + 8 * i;
        if (grow < n) {
            float4 r;
            r.x = acc[i].x + bv.x;
            r.y = acc[i].y + bv.y;
            r.z = acc[i].z + bv.z;
            r.w = acc[i].w + bv.w;
            if (RELU) {
                r.x = fmaxf(r.x, 0.f);
                r.y = fmaxf(r.y, 0.f);
                r.z = fmaxf(r.z, 0.f);
                r.w = fmaxf(r.w, 0.f);
            }
            Y4[grow * 32 + cg] = r;
        }
    }
}

// ---------------------------------------------------------------------------
// Kernel 6: per-column sum & sumsq of Y [N,128]
// ---------------------------------------------------------------------------
__global__ __launch_bounds__(256) void bn_stats_kernel(
    const float* __restrict__ Y, float* __restrict__ stats)
{
    const int cg = threadIdx.x & 31;
    const int rg = threadIdx.x >> 5;
    const float4* Y4 = (const float4*)Y;

    float4 s = make_float4(0.f, 0.f, 0.f, 0.f);
    float4 q = make_float4(0.f, 0.f, 0.f, 0.f);
    for (int r = blockIdx.x * 8 + rg; r < NN; r += gridDim.x * 8) {
        float4 v = Y4[r * 32 + cg];
        s.x += v.x; s.y += v.y; s.z += v.z; s.w += v.w;
        q.x += v.x * v.x; q.y += v.y * v.y; q.z += v.z * v.z; q.w += v.w * v.w;
    }

    __shared__ float4 ls[8][32];
    __shared__ float4 lq[8][32];
    ls[rg][cg] = s;
    lq[rg][cg] = q;
    __syncthreads();
    if (rg == 0) {
        float4 ts = ls[0][cg], tq = lq[0][cg];
#pragma unroll
        for (int i = 1; i < 8; ++i) {
            float4 a = ls[i][cg], b = lq[i][cg];
            ts.x += a.x; ts.y += a.y; ts.z += a.z; ts.w += a.w;
            tq.x += b.x; tq.y += b.y; tq.z += b.z; tq.w += b.w;
        }
        int c = cg << 2;
        atomicAdd(&stats[c + 0], ts.x);
        atomicAdd(&stats[c + 1], ts.y);
        atomicAdd(&stats[c + 2], ts.z);
        atomicAdd(&stats[c + 3], ts.w);
        atomicAdd(&stats[DD + c + 0], tq.x);
        atomicAdd(&stats[DD + c + 1], tq.y);
        atomicAdd(&stats[DD + c + 2], tq.z);
        atomicAdd(&stats[DD + c + 3], tq.w);
    }
}

// ---------------------------------------------------------------------------
// Kernel 7: out = h + relu((Y - mean) * rsqrt(var+eps) * gamma + beta)
// ---------------------------------------------------------------------------
__global__ __launch_bounds__(256) void bn_final_kernel(
    const float* __restrict__ Y, const float* __restrict__ h,
    const float* __restrict__ gamma, const float* __restrict__ beta,
    const float* __restrict__ stats, float* __restrict__ out)
{
    const float invN = 1.0f / (float)NN;
    const float4* Y4 = (const float4*)Y;
    const float4* H4 = (const float4*)h;
    float4* O4 = (float4*)out;
    const int total = NN * (DD / 4);
    for (int i = blockIdx.x * blockDim.x + threadIdx.x; i < total;
         i += gridDim.x * blockDim.x) {
        int cg = i & 31;
        int c = cg << 2;
        float4 v = Y4[i];
        float4 hv = H4[i];
        float4 g = ((const float4*)gamma)[cg];
        float4 bt = ((const float4*)beta)[cg];

        float m0 = stats[c + 0] * invN, m1 = stats[c + 1] * invN;
        float m2 = stats[c + 2] * invN, m3 = stats[c + 3] * invN;
        float v0 = stats[DD + c + 0] * invN - m0 * m0;
        float v1 = stats[DD + c + 1] * invN - m1 * m1;
        float v2 = stats[DD + c + 2] * invN - m2 * m2;
        float v3 = stats[DD + c + 3] * invN - m3 * m3;

        float4 r;
        r.x = hv.x + fmaxf((v.x - m0) * rsqrtf(v0 + BN_EPS) * g.x + bt.x, 0.f);
        r.y = hv.y + fmaxf((v.y - m1) * rsqrtf(v1 + BN_EPS) * g.y + bt.y, 0.f);
        r.z = hv.z + fmaxf((v.z - m2) * rsqrtf(v2 + BN_EPS) * g.z + bt.z, 0.f);
        r.w = hv.w + fmaxf((v.w - m3) * rsqrtf(v3 + BN_EPS) * g.w + bt.w, 0.f);
        O4[i] = r;
    }
}

// ---------------------------------------------------------------------------
extern "C" void kernel_launch(void* const* d_in, const int* in_sizes, int n_in,
                              void* d_out, int out_size, void* d_ws, size_t ws_size,
                              hipStream_t stream)
{
    const float* h     = (const float*)d_in[0];
    const int*   src   = (const int*)d_in[1];
    const int*   dst   = (const int*)d_in[2];
    const float* eps   = (const float*)d_in[3];
    const float* W1    = (const float*)d_in[4];
    const float* b1    = (const float*)d_in[5];
    const float* W2    = (const float*)d_in[6];
    const float* b2    = (const float*)d_in[7];
    const float* gamma = (const float*)d_in[8];
    const float* beta  = (const float*)d_in[9];
    float* out = (float*)d_out;

    // workspace layout (~7.6 MB)
    int* deg        = (int*)d_ws;
    int* off        = deg + NN;            // NN+1
    int* cursor     = off + (NN + 1);      // NN
    int* src_sorted = cursor + NN;         // NE
    float* stats    = (float*)(src_sorted + NE);  // 256 floats

    // 0. zero deg + stats
    zero_kernel<<<512, 256, 0, stream>>>(deg, stats);

    // 1. degree histogram
    hist_kernel<<<(NE + 255) / 256, 256, 0, stream>>>(dst, deg);

    // 2. exclusive scan -> off, cursor
    scan_kernel<<<1, 1024, 0, stream>>>(deg, off, cursor);

    // 3. bucket-scatter src indices into CSR order
    sort_edges_kernel<<<(NE + 255) / 256, 256, 0, stream>>>(src, dst, cursor, src_sorted);

    // 4. out = (1+eps)*h + neighbor-sum   (gather, no atomics)
    gather_sum_kernel<<<(NN + 7) / 8, 256, 0, stream>>>(h, eps, off, src_sorted, out);

    // 5. out = relu(out @ W1 + b1)   (in-place)
    int gemm_blocks = (NN + 63) / 64;  // 1563
    gemm128_kernel<true><<<gemm_blocks, 256, 0, stream>>>(out, W1, b1, out, NN);

    // 6. out = out @ W2 + b2   (in-place)
    gemm128_kernel<false><<<gemm_blocks, 256, 0, stream>>>(out, W2, b2, out, NN);

    // 7. BN stats
    bn_stats_kernel<<<512, 256, 0, stream>>>(out, stats);

    // 8. out = h + relu(BN(out))   (in-place)
    bn_final_kernel<<<1024, 256, 0, stream>>>(out, h, gamma, beta, stats, out);
}

// Round 3
// 712.730 us; speedup vs baseline: 4.3372x; 1.3367x over previous
//
#include <hip/hip_runtime.h>

#define NN 100000
#define NE 1600000
#define DD 128
#define BN_EPS 1e-5f

#define SCAN_CHUNK 512
#define SCAN_BLOCKS ((NN + SCAN_CHUNK - 1) / SCAN_CHUNK)  // 196

// ---------------------------------------------------------------------------
// Kernel 0: zero deg[] and stats[]
// ---------------------------------------------------------------------------
__global__ __launch_bounds__(256) void zero_kernel(
    int* __restrict__ deg, float* __restrict__ stats)
{
    for (int i = blockIdx.x * blockDim.x + threadIdx.x; i < NN;
         i += gridDim.x * blockDim.x)
        deg[i] = 0;
    if (blockIdx.x == 0 && threadIdx.x < 2 * DD) stats[threadIdx.x] = 0.0f;
}

// ---------------------------------------------------------------------------
// Kernel 1: histogram of dst
// ---------------------------------------------------------------------------
__global__ __launch_bounds__(256) void hist_kernel(
    const int* __restrict__ dst, int* __restrict__ deg)
{
    int e = blockIdx.x * blockDim.x + threadIdx.x;
    if (e < NE) atomicAdd(&deg[dst[e]], 1);
}

// ---------------------------------------------------------------------------
// Scan phase 1: per-block (512-elem chunk) sum of deg -> bsum[196]
// ---------------------------------------------------------------------------
__global__ __launch_bounds__(256) void scan_bsum_kernel(
    const int* __restrict__ deg, int* __restrict__ bsum)
{
    __shared__ int sdata[256];
    int t = threadIdx.x;
    int j0 = blockIdx.x * SCAN_CHUNK + t * 2;
    int v = 0;
    if (j0 < NN) v += deg[j0];
    if (j0 + 1 < NN) v += deg[j0 + 1];
    sdata[t] = v;
    __syncthreads();
#pragma unroll
    for (int s = 128; s > 0; s >>= 1) {
        if (t < s) sdata[t] += sdata[t + s];
        __syncthreads();
    }
    if (t == 0) bsum[blockIdx.x] = sdata[0];
}

// ---------------------------------------------------------------------------
// Scan phase 2: single block exclusive-scans bsum[196] in place
// ---------------------------------------------------------------------------
__global__ __launch_bounds__(256) void scan_spine_kernel(int* __restrict__ bsum)
{
    __shared__ int part[256];
    int t = threadIdx.x;
    int v = (t < SCAN_BLOCKS) ? bsum[t] : 0;
    part[t] = v;
    __syncthreads();
#pragma unroll
    for (int ofs = 1; ofs < 256; ofs <<= 1) {
        int u = (t >= ofs) ? part[t - ofs] : 0;
        __syncthreads();
        part[t] += u;
        __syncthreads();
    }
    if (t < SCAN_BLOCKS) bsum[t] = part[t] - v;  // exclusive
}

// ---------------------------------------------------------------------------
// Scan phase 3: block-level exclusive scan + spine offset -> off, cursor
// ---------------------------------------------------------------------------
__global__ __launch_bounds__(256) void scan_apply_kernel(
    const int* __restrict__ deg, const int* __restrict__ bsum,
    int* __restrict__ off, int* __restrict__ cursor)
{
    __shared__ int part[256];
    int t = threadIdx.x;
    int j0 = blockIdx.x * SCAN_CHUNK + t * 2;
    int d0 = (j0 < NN) ? deg[j0] : 0;
    int d1 = (j0 + 1 < NN) ? deg[j0 + 1] : 0;
    int ps = d0 + d1;
    part[t] = ps;
    __syncthreads();
#pragma unroll
    for (int ofs = 1; ofs < 256; ofs <<= 1) {
        int u = (t >= ofs) ? part[t - ofs] : 0;
        __syncthreads();
        part[t] += u;
        __syncthreads();
    }
    int excl = part[t] - ps + bsum[blockIdx.x];
    if (j0 < NN) { off[j0] = excl; cursor[j0] = excl; }
    if (j0 + 1 < NN) { off[j0 + 1] = excl + d0; cursor[j0 + 1] = excl + d0; }
    if (blockIdx.x == 0 && t == 0) off[NN] = NE;
}

// ---------------------------------------------------------------------------
// Kernel 3: bucket-scatter edge sources into CSR order
// ---------------------------------------------------------------------------
__global__ __launch_bounds__(256) void sort_edges_kernel(
    const int* __restrict__ src, const int* __restrict__ dst,
    int* __restrict__ cursor, int* __restrict__ src_sorted)
{
    int e = blockIdx.x * blockDim.x + threadIdx.x;
    if (e < NE) {
        int pos = atomicAdd(&cursor[dst[e]], 1);
        src_sorted[pos] = src[e];
    }
}

// ---------------------------------------------------------------------------
// Kernel 4: out[n,:] = (1+eps)*h[n,:] + sum_{e in CSR[n]} h[src_sorted[e],:]
// 32 threads per node (float4 each), 8 nodes per 256-thread block.
// ---------------------------------------------------------------------------
__global__ __launch_bounds__(256) void gather_sum_kernel(
    const float* __restrict__ h, const float* __restrict__ eps,
    const int* __restrict__ off, const int* __restrict__ src_sorted,
    float* __restrict__ out)
{
    int node = blockIdx.x * 8 + (threadIdx.x >> 5);
    if (node >= NN) return;
    int c4 = threadIdx.x & 31;
    const float4* h4 = (const float4*)h;

    const float s = 1.0f + eps[0];
    float4 a = h4[node * 32 + c4];
    a.x *= s; a.y *= s; a.z *= s; a.w *= s;

    int e = off[node];
    int eend = off[node + 1];
    for (; e + 1 < eend; e += 2) {
        int s0 = src_sorted[e];
        int s1 = src_sorted[e + 1];
        float4 v0 = h4[s0 * 32 + c4];
        float4 v1 = h4[s1 * 32 + c4];
        a.x += v0.x + v1.x;
        a.y += v0.y + v1.y;
        a.z += v0.z + v1.z;
        a.w += v0.w + v1.w;
    }
    if (e < eend) {
        int s0 = src_sorted[e];
        float4 v0 = h4[s0 * 32 + c4];
        a.x += v0.x; a.y += v0.y; a.z += v0.z; a.w += v0.w;
    }
    ((float4*)out)[node * 32 + c4] = a;
}

// ---------------------------------------------------------------------------
// Kernel 5: Y = (relu?)(X @ W + b)  for D=128. Block = 64 rows x 128 cols,
// 256 threads. In-place safe (block reads only its own rows; all global
// reads precede its writes).
// ---------------------------------------------------------------------------
template <bool RELU>
__global__ __launch_bounds__(256) void gemm128_kernel(
    const float* __restrict__ X, const float* __restrict__ W,
    const float* __restrict__ bias, float* __restrict__ Y, int n)
{
    __shared__ float xs[64][32];    // 8 KB
    __shared__ float wsm[32][128];  // 16 KB

    const int tid = threadIdx.x;
    const int cg = tid & 31;
    const int rg = tid >> 5;
    const int r0 = blockIdx.x * 64;

    const float4* X4 = (const float4*)X;
    const float4* W4 = (const float4*)W;
    float4* Y4 = (float4*)Y;

    float4 acc[8];
#pragma unroll
    for (int i = 0; i < 8; ++i) acc[i] = make_float4(0.f, 0.f, 0.f, 0.f);

    for (int kb = 0; kb < 4; ++kb) {
#pragma unroll
        for (int l = 0; l < 2; ++l) {
            int j = tid + l * 256;
            int row = j >> 3;
            int kc = j & 7;
            int grow = r0 + row;
            float4 v = make_float4(0.f, 0.f, 0.f, 0.f);
            if (grow < n) v = X4[grow * 32 + kb * 8 + kc];
            *(float4*)&xs[row][kc << 2] = v;
        }
#pragma unroll
        for (int l = 0; l < 4; ++l) {
            int j = tid + l * 256;
            int kr = j >> 5;
            int kc = j & 31;
            *(float4*)&wsm[kr][kc << 2] = W4[(kb * 32 + kr) * 32 + kc];
        }
        __syncthreads();

#pragma unroll
        for (int k4 = 0; k4 < 8; ++k4) {
            float4 w0 = *(const float4*)&wsm[k4 * 4 + 0][cg << 2];
            float4 w1 = *(const float4*)&wsm[k4 * 4 + 1][cg << 2];
            float4 w2 = *(const float4*)&wsm[k4 * 4 + 2][cg << 2];
            float4 w3 = *(const float4*)&wsm[k4 * 4 + 3][cg << 2];
#pragma unroll
            for (int i = 0; i < 8; ++i) {
                float4 xv = *(const float4*)&xs[rg + 8 * i][k4 << 2];
                acc[i].x += xv.x * w0.x + xv.y * w1.x + xv.z * w2.x + xv.w * w3.x;
                acc[i].y += xv.x * w0.y + xv.y * w1.y + xv.z * w2.y + xv.w * w3.y;
                acc[i].z += xv.x * w0.z + xv.y * w1.z + xv.z * w2.z + xv.w * w3.z;
                acc[i].w += xv.x * w0.w + xv.y * w1.w + xv.z * w2.w + xv.w * w3.w;
            }
        }
        __syncthreads();
    }

    float4 bv = ((const float4*)bias)[cg];
#pragma unroll
    for (int i = 0; i < 8; ++i) {
        int grow = r0 + rg + 8 * i;
        if (grow < n) {
            float4 r;
            r.x = acc[i].x + bv.x;
            r.y = acc[i].y + bv.y;
            r.z = acc[i].z + bv.z;
            r.w = acc[i].w + bv.w;
            if (RELU) {
                r.x = fmaxf(r.x, 0.f);
                r.y = fmaxf(r.y, 0.f);
                r.z = fmaxf(r.z, 0.f);
                r.w = fmaxf(r.w, 0.f);
            }
            Y4[grow * 32 + cg] = r;
        }
    }
}

// ---------------------------------------------------------------------------
// Kernel 6: per-column sum & sumsq of Y [N,128]
// ---------------------------------------------------------------------------
__global__ __launch_bounds__(256) void bn_stats_kernel(
    const float* __restrict__ Y, float* __restrict__ stats)
{
    const int cg = threadIdx.x & 31;
    const int rg = threadIdx.x >> 5;
    const float4* Y4 = (const float4*)Y;

    float4 s = make_float4(0.f, 0.f, 0.f, 0.f);
    float4 q = make_float4(0.f, 0.f, 0.f, 0.f);
    for (int r = blockIdx.x * 8 + rg; r < NN; r += gridDim.x * 8) {
        float4 v = Y4[r * 32 + cg];
        s.x += v.x; s.y += v.y; s.z += v.z; s.w += v.w;
        q.x += v.x * v.x; q.y += v.y * v.y; q.z += v.z * v.z; q.w += v.w * v.w;
    }

    __shared__ float4 ls[8][32];
    __shared__ float4 lq[8][32];
    ls[rg][cg] = s;
    lq[rg][cg] = q;
    __syncthreads();
    if (rg == 0) {
        float4 ts = ls[0][cg], tq = lq[0][cg];
#pragma unroll
        for (int i = 1; i < 8; ++i) {
            float4 a = ls[i][cg], b = lq[i][cg];
            ts.x += a.x; ts.y += a.y; ts.z += a.z; ts.w += a.w;
            tq.x += b.x; tq.y += b.y; tq.z += b.z; tq.w += b.w;
        }
        int c = cg << 2;
        atomicAdd(&stats[c + 0], ts.x);
        atomicAdd(&stats[c + 1], ts.y);
        atomicAdd(&stats[c + 2], ts.z);
        atomicAdd(&stats[c + 3], ts.w);
        atomicAdd(&stats[DD + c + 0], tq.x);
        atomicAdd(&stats[DD + c + 1], tq.y);
        atomicAdd(&stats[DD + c + 2], tq.z);
        atomicAdd(&stats[DD + c + 3], tq.w);
    }
}

// ---------------------------------------------------------------------------
// Kernel 7: out = h + relu((Y - mean) * rsqrt(var+eps) * gamma + beta)
// ---------------------------------------------------------------------------
__global__ __launch_bounds__(256) void bn_final_kernel(
    const float* __restrict__ Y, const float* __restrict__ h,
    const float* __restrict__ gamma, const float* __restrict__ beta,
    const float* __restrict__ stats, float* __restrict__ out)
{
    const float invN = 1.0f / (float)NN;
    const float4* Y4 = (const float4*)Y;
    const float4* H4 = (const float4*)h;
    float4* O4 = (float4*)out;
    const int total = NN * (DD / 4);
    for (int i = blockIdx.x * blockDim.x + threadIdx.x; i < total;
         i += gridDim.x * blockDim.x) {
        int cg = i & 31;
        int c = cg << 2;
        float4 v = Y4[i];
        float4 hv = H4[i];
        float4 g = ((const float4*)gamma)[cg];
        float4 bt = ((const float4*)beta)[cg];

        float m0 = stats[c + 0] * invN, m1 = stats[c + 1] * invN;
        float m2 = stats[c + 2] * invN, m3 = stats[c + 3] * invN;
        float v0 = stats[DD + c + 0] * invN - m0 * m0;
        float v1 = stats[DD + c + 1] * invN - m1 * m1;
        float v2 = stats[DD + c + 2] * invN - m2 * m2;
        float v3 = stats[DD + c + 3] * invN - m3 * m3;

        float4 r;
        r.x = hv.x + fmaxf((v.x - m0) * rsqrtf(v0 + BN_EPS) * g.x + bt.x, 0.f);
        r.y = hv.y + fmaxf((v.y - m1) * rsqrtf(v1 + BN_EPS) * g.y + bt.y, 0.f);
        r.z = hv.z + fmaxf((v.z - m2) * rsqrtf(v2 + BN_EPS) * g.z + bt.z, 0.f);
        r.w = hv.w + fmaxf((v.w - m3) * rsqrtf(v3 + BN_EPS) * g.w + bt.w, 0.f);
        O4[i] = r;
    }
}

// ---------------------------------------------------------------------------
extern "C" void kernel_launch(void* const* d_in, const int* in_sizes, int n_in,
                              void* d_out, int out_size, void* d_ws, size_t ws_size,
                              hipStream_t stream)
{
    const float* h     = (const float*)d_in[0];
    const int*   src   = (const int*)d_in[1];
    const int*   dst   = (const int*)d_in[2];
    const float* eps   = (const float*)d_in[3];
    const float* W1    = (const float*)d_in[4];
    const float* b1    = (const float*)d_in[5];
    const float* W2    = (const float*)d_in[6];
    const float* b2    = (const float*)d_in[7];
    const float* gamma = (const float*)d_in[8];
    const float* beta  = (const float*)d_in[9];
    float* out = (float*)d_out;

    // workspace layout (~7.6 MB)
    int* deg        = (int*)d_ws;
    int* off        = deg + NN;            // NN+1
    int* cursor     = off + (NN + 1);      // NN
    int* src_sorted = cursor + NN;         // NE
    float* stats    = (float*)(src_sorted + NE);  // 256 floats
    int* bsum       = (int*)(stats + 2 * DD);     // SCAN_BLOCKS ints

    // 0. zero deg + stats
    zero_kernel<<<512, 256, 0, stream>>>(deg, stats);

    // 1. degree histogram
    hist_kernel<<<(NE + 255) / 256, 256, 0, stream>>>(dst, deg);

    // 2. parallel exclusive scan -> off, cursor
    scan_bsum_kernel<<<SCAN_BLOCKS, 256, 0, stream>>>(deg, bsum);
    scan_spine_kernel<<<1, 256, 0, stream>>>(bsum);
    scan_apply_kernel<<<SCAN_BLOCKS, 256, 0, stream>>>(deg, bsum, off, cursor);

    // 3. bucket-scatter src indices into CSR order
    sort_edges_kernel<<<(NE + 255) / 256, 256, 0, stream>>>(src, dst, cursor, src_sorted);

    // 4. out = (1+eps)*h + neighbor-sum   (gather, no atomics)
    gather_sum_kernel<<<(NN + 7) / 8, 256, 0, stream>>>(h, eps, off, src_sorted, out);

    // 5. out = relu(out @ W1 + b1)   (in-place)
    int gemm_blocks = (NN + 63) / 64;  // 1563
    gemm128_kernel<true><<<gemm_blocks, 256, 0, stream>>>(out, W1, b1, out, NN);

    // 6. out = out @ W2 + b2   (in-place)
    gemm128_kernel<false><<<gemm_blocks, 256, 0, stream>>>(out, W2, b2, out, NN);

    // 7. BN stats
    bn_stats_kernel<<<512, 256, 0, stream>>>(out, stats);

    // 8. out = h + relu(BN(out))   (in-place)
    bn_final_kernel<<<1024, 256, 0, stream>>>(out, h, gamma, beta, stats, out);
}

// Round 4
// 524.718 us; speedup vs baseline: 5.8912x; 1.3583x over previous
//
#include <hip/hip_runtime.h>

#define NN 100000
#define NE 1600000
#define DD 128
#define BN_EPS 1e-5f

#define SCAN_CHUNK 512
#define SCAN_BLOCKS ((NN + SCAN_CHUNK - 1) / SCAN_CHUNK)  // 196

typedef __attribute__((ext_vector_type(8))) short short8;
typedef __attribute__((ext_vector_type(4))) float floatx4;

__device__ __forceinline__ unsigned short f2bf(float f) {
    union { float f; unsigned u; } v; v.f = f;
    return (unsigned short)((v.u + 0x7FFFu + ((v.u >> 16) & 1u)) >> 16);
}
__device__ __forceinline__ float bf2f(unsigned short u) {
    union { unsigned u; float f; } v; v.u = ((unsigned)u) << 16;
    return v.f;
}

// ---------------------------------------------------------------------------
// Kernel 0: zero deg/stats; W1,W2 -> bf16 transposed [n][k]; optional h->bf16
// ---------------------------------------------------------------------------
__global__ __launch_bounds__(256) void prep_kernel(
    int* __restrict__ deg, float* __restrict__ stats,
    const float* __restrict__ W1, const float* __restrict__ W2,
    unsigned short* __restrict__ W1t, unsigned short* __restrict__ W2t,
    const float* __restrict__ h, unsigned short* __restrict__ hb, int do_hb)
{
    int tid0 = blockIdx.x * blockDim.x + threadIdx.x;
    int stride = gridDim.x * blockDim.x;
    for (int i = tid0; i < NN; i += stride) deg[i] = 0;
    if (tid0 < 2 * DD) stats[tid0] = 0.0f;
    for (int i = tid0; i < DD * DD; i += stride) {
        int n = i >> 7, k = i & 127;
        W1t[i] = f2bf(W1[k * DD + n]);
        W2t[i] = f2bf(W2[k * DD + n]);
    }
    if (do_hb) {
        const float4* h4 = (const float4*)h;
        ushort4* hb4 = (ushort4*)hb;
        for (int i = tid0; i < NN * (DD / 4); i += stride) {
            float4 v = h4[i];
            ushort4 o;
            o.x = f2bf(v.x); o.y = f2bf(v.y); o.z = f2bf(v.z); o.w = f2bf(v.w);
            hb4[i] = o;
        }
    }
}

// ---------------------------------------------------------------------------
// Kernel 1: histogram of dst
// ---------------------------------------------------------------------------
__global__ __launch_bounds__(256) void hist_kernel(
    const int* __restrict__ dst, int* __restrict__ deg)
{
    int e = blockIdx.x * blockDim.x + threadIdx.x;
    if (e < NE) atomicAdd(&deg[dst[e]], 1);
}

// ---------------------------------------------------------------------------
// Scan phase 1: per-block (512-elem chunk) sum of deg -> bsum
// ---------------------------------------------------------------------------
__global__ __launch_bounds__(256) void scan_bsum_kernel(
    const int* __restrict__ deg, int* __restrict__ bsum)
{
    __shared__ int sdata[256];
    int t = threadIdx.x;
    int j0 = blockIdx.x * SCAN_CHUNK + t * 2;
    int v = 0;
    if (j0 < NN) v += deg[j0];
    if (j0 + 1 < NN) v += deg[j0 + 1];
    sdata[t] = v;
    __syncthreads();
#pragma unroll
    for (int s = 128; s > 0; s >>= 1) {
        if (t < s) sdata[t] += sdata[t + s];
        __syncthreads();
    }
    if (t == 0) bsum[blockIdx.x] = sdata[0];
}

// ---------------------------------------------------------------------------
// Scan phase 2: single block exclusive-scans bsum in place
// ---------------------------------------------------------------------------
__global__ __launch_bounds__(256) void scan_spine_kernel(int* __restrict__ bsum)
{
    __shared__ int part[256];
    int t = threadIdx.x;
    int v = (t < SCAN_BLOCKS) ? bsum[t] : 0;
    part[t] = v;
    __syncthreads();
#pragma unroll
    for (int ofs = 1; ofs < 256; ofs <<= 1) {
        int u = (t >= ofs) ? part[t - ofs] : 0;
        __syncthreads();
        part[t] += u;
        __syncthreads();
    }
    if (t < SCAN_BLOCKS) bsum[t] = part[t] - v;
}

// ---------------------------------------------------------------------------
// Scan phase 3: block-level exclusive scan + spine offset -> off, cursor
// ---------------------------------------------------------------------------
__global__ __launch_bounds__(256) void scan_apply_kernel(
    const int* __restrict__ deg, const int* __restrict__ bsum,
    int* __restrict__ off, int* __restrict__ cursor)
{
    __shared__ int part[256];
    int t = threadIdx.x;
    int j0 = blockIdx.x * SCAN_CHUNK + t * 2;
    int d0 = (j0 < NN) ? deg[j0] : 0;
    int d1 = (j0 + 1 < NN) ? deg[j0 + 1] : 0;
    int ps = d0 + d1;
    part[t] = ps;
    __syncthreads();
#pragma unroll
    for (int ofs = 1; ofs < 256; ofs <<= 1) {
        int u = (t >= ofs) ? part[t - ofs] : 0;
        __syncthreads();
        part[t] += u;
        __syncthreads();
    }
    int excl = part[t] - ps + bsum[blockIdx.x];
    if (j0 < NN) { off[j0] = excl; cursor[j0] = excl; }
    if (j0 + 1 < NN) { off[j0 + 1] = excl + d0; cursor[j0 + 1] = excl + d0; }
    if (blockIdx.x == 0 && t == 0) off[NN] = NE;
}

// ---------------------------------------------------------------------------
// Kernel 3: bucket-scatter edge sources into CSR order
// ---------------------------------------------------------------------------
__global__ __launch_bounds__(256) void sort_edges_kernel(
    const int* __restrict__ src, const int* __restrict__ dst,
    int* __restrict__ cursor, int* __restrict__ src_sorted)
{
    int e = blockIdx.x * blockDim.x + threadIdx.x;
    if (e < NE) {
        int pos = atomicAdd(&cursor[dst[e]], 1);
        src_sorted[pos] = src[e];
    }
}

// ---------------------------------------------------------------------------
// Kernel 4a: gather-sum reading bf16 h copy, writing bf16 x
// ---------------------------------------------------------------------------
__global__ __launch_bounds__(256) void gather_bf16_kernel(
    const float* __restrict__ h, const unsigned short* __restrict__ hb,
    const float* __restrict__ eps, const int* __restrict__ off,
    const int* __restrict__ src_sorted, unsigned short* __restrict__ xb)
{
    int node = blockIdx.x * 8 + (threadIdx.x >> 5);
    if (node >= NN) return;
    int c4 = threadIdx.x & 31;
    const float s = 1.0f + eps[0];
    float4 hv = ((const float4*)h)[node * 32 + c4];
    float ax = s * hv.x, ay = s * hv.y, az = s * hv.z, aw = s * hv.w;
    const ushort4* hb4 = (const ushort4*)hb;
    int e = off[node], eend = off[node + 1];
    for (; e + 1 < eend; e += 2) {
        int s0 = src_sorted[e], s1 = src_sorted[e + 1];
        ushort4 v0 = hb4[s0 * 32 + c4];
        ushort4 v1 = hb4[s1 * 32 + c4];
        ax += bf2f(v0.x) + bf2f(v1.x);
        ay += bf2f(v0.y) + bf2f(v1.y);
        az += bf2f(v0.z) + bf2f(v1.z);
        aw += bf2f(v0.w) + bf2f(v1.w);
    }
    if (e < eend) {
        ushort4 v0 = hb4[src_sorted[e] * 32 + c4];
        ax += bf2f(v0.x); ay += bf2f(v0.y); az += bf2f(v0.z); aw += bf2f(v0.w);
    }
    ushort4 o;
    o.x = f2bf(ax); o.y = f2bf(ay); o.z = f2bf(az); o.w = f2bf(aw);
    ((ushort4*)xb)[node * 32 + c4] = o;
}

// ---------------------------------------------------------------------------
// Kernel 4b: gather-sum reading fp32 h (fallback if ws too small for hb)
// ---------------------------------------------------------------------------
__global__ __launch_bounds__(256) void gather_f32_kernel(
    const float* __restrict__ h, const float* __restrict__ eps,
    const int* __restrict__ off, const int* __restrict__ src_sorted,
    unsigned short* __restrict__ xb)
{
    int node = blockIdx.x * 8 + (threadIdx.x >> 5);
    if (node >= NN) return;
    int c4 = threadIdx.x & 31;
    const float4* h4 = (const float4*)h;
    const float s = 1.0f + eps[0];
    float4 hv = h4[node * 32 + c4];
    float ax = s * hv.x, ay = s * hv.y, az = s * hv.z, aw = s * hv.w;
    int e = off[node], eend = off[node + 1];
    for (; e + 1 < eend; e += 2) {
        float4 v0 = h4[src_sorted[e] * 32 + c4];
        float4 v1 = h4[src_sorted[e + 1] * 32 + c4];
        ax += v0.x + v1.x; ay += v0.y + v1.y;
        az += v0.z + v1.z; aw += v0.w + v1.w;
    }
    if (e < eend) {
        float4 v0 = h4[src_sorted[e] * 32 + c4];
        ax += v0.x; ay += v0.y; az += v0.z; aw += v0.w;
    }
    ushort4 o;
    o.x = f2bf(ax); o.y = f2bf(ay); o.z = f2bf(az); o.w = f2bf(aw);
    ((ushort4*)xb)[node * 32 + c4] = o;
}

// ---------------------------------------------------------------------------
// Kernel 5: bf16 MFMA GEMM: Y = (relu?)(X @ W + b), X [NN][128] bf16,
// Wt [n][k] bf16 pre-transposed, Y bf16. Block = 64 rows, 4 waves.
// Wave wv owns rows [wv*16, wv*16+16); 8 col-tiles; K in 4 chunks of 32.
// In-place safe (block reads only its own 64 rows into LDS before writing).
// A-frag: A[m=lane&15][k=(lane>>4)*8+j]; B-frag: B[k][n=lane&15];
// C/D: col=lane&15, row=(lane>>4)*4+reg.
// ---------------------------------------------------------------------------
template <bool RELU>
__global__ __launch_bounds__(256) void gemm_mfma_kernel(
    const unsigned short* __restrict__ X, const unsigned short* __restrict__ Wt,
    const float* __restrict__ bias, unsigned short* __restrict__ Y)
{
    extern __shared__ char smem[];
    unsigned short* wl = (unsigned short*)smem;            // [128][136] bf16
    unsigned short* xl = (unsigned short*)(smem + 34816);  // [64][136] bf16

    const int tid = threadIdx.x;
    const int r0 = blockIdx.x * 64;
    const int lane = tid & 63;
    const int wv = tid >> 6;
    const int m = lane & 15;
    const int hi = lane >> 4;

    // stage Wt (128x128 bf16) -> LDS [128][136]
    const short8* Wt8 = (const short8*)Wt;
#pragma unroll
    for (int l = 0; l < 8; ++l) {
        int idx = tid + l * 256;
        int n = idx >> 4, c = idx & 15;
        *(short8*)&wl[n * 136 + c * 8] = Wt8[idx];
    }
    // stage X tile (64x128 bf16) -> LDS [64][136]
    const short8* X8 = (const short8*)X;
#pragma unroll
    for (int l = 0; l < 4; ++l) {
        int idx = tid + l * 256;
        int row = idx >> 4, c = idx & 15;
        int g = r0 + row;
        short8 v = {0, 0, 0, 0, 0, 0, 0, 0};
        if (g < NN) v = X8[g * 16 + c];
        *(short8*)&xl[row * 136 + c * 8] = v;
    }
    __syncthreads();

    floatx4 acc[8];
#pragma unroll
    for (int i = 0; i < 8; ++i) acc[i] = (floatx4){0.f, 0.f, 0.f, 0.f};

#pragma unroll
    for (int kc = 0; kc < 4; ++kc) {
        short8 a = *(const short8*)&xl[(wv * 16 + m) * 136 + kc * 32 + hi * 8];
#pragma unroll
        for (int nt = 0; nt < 8; ++nt) {
            short8 b = *(const short8*)&wl[(nt * 16 + m) * 136 + kc * 32 + hi * 8];
            acc[nt] = __builtin_amdgcn_mfma_f32_16x16x32_bf16(a, b, acc[nt], 0, 0, 0);
        }
    }
    __syncthreads();  // xl now free; reuse as C tile

    unsigned short* cl = xl;  // [64][136] bf16
#pragma unroll
    for (int nt = 0; nt < 8; ++nt) {
        float bv = bias[nt * 16 + m];
#pragma unroll
        for (int r = 0; r < 4; ++r) {
            float v = acc[nt][r] + bv;
            if (RELU) v = fmaxf(v, 0.f);
            cl[(wv * 16 + hi * 4 + r) * 136 + nt * 16 + m] = f2bf(v);
        }
    }
    __syncthreads();

#pragma unroll
    for (int l = 0; l < 4; ++l) {
        int idx = tid + l * 256;
        int row = idx >> 4, c = idx & 15;
        int g = r0 + row;
        if (g < NN)
            ((short8*)Y)[g * 16 + c] = *(const short8*)&cl[row * 136 + c * 8];
    }
}

// ---------------------------------------------------------------------------
// Kernel 6: per-column sum & sumsq of bf16 Y [N,128]
// ---------------------------------------------------------------------------
__global__ __launch_bounds__(256) void bn_stats_kernel(
    const unsigned short* __restrict__ Y, float* __restrict__ stats)
{
    const int cg = threadIdx.x & 31;
    const int rg = threadIdx.x >> 5;
    const ushort4* Y4 = (const ushort4*)Y;

    float4 s = make_float4(0.f, 0.f, 0.f, 0.f);
    float4 q = make_float4(0.f, 0.f, 0.f, 0.f);
    for (int r = blockIdx.x * 8 + rg; r < NN; r += gridDim.x * 8) {
        ushort4 u = Y4[r * 32 + cg];
        float vx = bf2f(u.x), vy = bf2f(u.y), vz = bf2f(u.z), vw = bf2f(u.w);
        s.x += vx; s.y += vy; s.z += vz; s.w += vw;
        q.x += vx * vx; q.y += vy * vy; q.z += vz * vz; q.w += vw * vw;
    }

    __shared__ float4 ls[8][32];
    __shared__ float4 lq[8][32];
    ls[rg][cg] = s;
    lq[rg][cg] = q;
    __syncthreads();
    if (rg == 0) {
        float4 ts = ls[0][cg], tq = lq[0][cg];
#pragma unroll
        for (int i = 1; i < 8; ++i) {
            float4 a = ls[i][cg], b = lq[i][cg];
            ts.x += a.x; ts.y += a.y; ts.z += a.z; ts.w += a.w;
            tq.x += b.x; tq.y += b.y; tq.z += b.z; tq.w += b.w;
        }
        int c = cg << 2;
        atomicAdd(&stats[c + 0], ts.x);
        atomicAdd(&stats[c + 1], ts.y);
        atomicAdd(&stats[c + 2], ts.z);
        atomicAdd(&stats[c + 3], ts.w);
        atomicAdd(&stats[DD + c + 0], tq.x);
        atomicAdd(&stats[DD + c + 1], tq.y);
        atomicAdd(&stats[DD + c + 2], tq.z);
        atomicAdd(&stats[DD + c + 3], tq.w);
    }
}

// ---------------------------------------------------------------------------
// Kernel 7: out = h + relu((Y - mean) * rsqrt(var+eps) * gamma + beta)
// ---------------------------------------------------------------------------
__global__ __launch_bounds__(256) void bn_final_kernel(
    const unsigned short* __restrict__ Y, const float* __restrict__ h,
    const float* __restrict__ gamma, const float* __restrict__ beta,
    const float* __restrict__ stats, float* __restrict__ out)
{
    const float invN = 1.0f / (float)NN;
    const ushort4* Y4 = (const ushort4*)Y;
    const float4* H4 = (const float4*)h;
    float4* O4 = (float4*)out;
    const int total = NN * (DD / 4);
    for (int i = blockIdx.x * blockDim.x + threadIdx.x; i < total;
         i += gridDim.x * blockDim.x) {
        int cg = i & 31;
        int c = cg << 2;
        ushort4 u = Y4[i];
        float4 hv = H4[i];
        float4 g = ((const float4*)gamma)[cg];
        float4 bt = ((const float4*)beta)[cg];

        float m0 = stats[c + 0] * invN, m1 = stats[c + 1] * invN;
        float m2 = stats[c + 2] * invN, m3 = stats[c + 3] * invN;
        float v0 = stats[DD + c + 0] * invN - m0 * m0;
        float v1 = stats[DD + c + 1] * invN - m1 * m1;
        float v2 = stats[DD + c + 2] * invN - m2 * m2;
        float v3 = stats[DD + c + 3] * invN - m3 * m3;

        float4 r;
        r.x = hv.x + fmaxf((bf2f(u.x) - m0) * rsqrtf(v0 + BN_EPS) * g.x + bt.x, 0.f);
        r.y = hv.y + fmaxf((bf2f(u.y) - m1) * rsqrtf(v1 + BN_EPS) * g.y + bt.y, 0.f);
        r.z = hv.z + fmaxf((bf2f(u.z) - m2) * rsqrtf(v2 + BN_EPS) * g.z + bt.z, 0.f);
        r.w = hv.w + fmaxf((bf2f(u.w) - m3) * rsqrtf(v3 + BN_EPS) * g.w + bt.w, 0.f);
        O4[i] = r;
    }
}

// ---------------------------------------------------------------------------
extern "C" void kernel_launch(void* const* d_in, const int* in_sizes, int n_in,
                              void* d_out, int out_size, void* d_ws, size_t ws_size,
                              hipStream_t stream)
{
    const float* h     = (const float*)d_in[0];
    const int*   src   = (const int*)d_in[1];
    const int*   dst   = (const int*)d_in[2];
    const float* eps   = (const float*)d_in[3];
    const float* W1    = (const float*)d_in[4];
    const float* b1    = (const float*)d_in[5];
    const float* W2    = (const float*)d_in[6];
    const float* b2    = (const float*)d_in[7];
    const float* gamma = (const float*)d_in[8];
    const float* beta  = (const float*)d_in[9];
    float* out = (float*)d_out;

    // workspace layout — every segment a multiple of 16 B to keep 16B aligns
    char* w = (char*)d_ws;
    size_t o = 0;
    int* deg        = (int*)(w + o); o += (size_t)NN * 4;        // 400000
    int* off        = (int*)(w + o); o += (size_t)(NN + 4) * 4;  // 400016
    int* cursor     = (int*)(w + o); o += (size_t)NN * 4;
    int* src_sorted = (int*)(w + o); o += (size_t)NE * 4;
    float* stats    = (float*)(w + o); o += 256 * 4;
    int* bsum       = (int*)(w + o); o += 256 * 4;
    unsigned short* W1t = (unsigned short*)(w + o); o += (size_t)DD * DD * 2;
    unsigned short* W2t = (unsigned short*)(w + o); o += (size_t)DD * DD * 2;
    unsigned short* xb  = (unsigned short*)(w + o); o += (size_t)NN * DD * 2;
    unsigned short* hb  = (unsigned short*)(w + o); o += (size_t)NN * DD * 2;
    const int use_hb = (ws_size >= o) ? 1 : 0;  // launch-constant: same every call

    // 0. zero deg/stats, build bf16 transposed weights (+ bf16 h copy)
    prep_kernel<<<512, 256, 0, stream>>>(deg, stats, W1, W2, W1t, W2t, h, hb, use_hb);

    // 1. degree histogram
    hist_kernel<<<(NE + 255) / 256, 256, 0, stream>>>(dst, deg);

    // 2. parallel exclusive scan -> off, cursor
    scan_bsum_kernel<<<SCAN_BLOCKS, 256, 0, stream>>>(deg, bsum);
    scan_spine_kernel<<<1, 256, 0, stream>>>(bsum);
    scan_apply_kernel<<<SCAN_BLOCKS, 256, 0, stream>>>(deg, bsum, off, cursor);

    // 3. bucket-scatter src indices into CSR order
    sort_edges_kernel<<<(NE + 255) / 256, 256, 0, stream>>>(src, dst, cursor, src_sorted);

    // 4. xb = bf16((1+eps)*h + neighbor-sum)
    if (use_hb)
        gather_bf16_kernel<<<(NN + 7) / 8, 256, 0, stream>>>(h, hb, eps, off, src_sorted, xb);
    else
        gather_f32_kernel<<<(NN + 7) / 8, 256, 0, stream>>>(h, eps, off, src_sorted, xb);

    // 5/6. MLP via bf16 MFMA, in-place on xb
    int gemm_blocks = (NN + 63) / 64;  // 1563
    size_t gemm_lds = 34816 + 17408;   // 52224 B -> 3 blocks/CU
    gemm_mfma_kernel<true><<<gemm_blocks, 256, gemm_lds, stream>>>(xb, W1t, b1, xb);
    gemm_mfma_kernel<false><<<gemm_blocks, 256, gemm_lds, stream>>>(xb, W2t, b2, xb);

    // 7. BN stats over bf16 y2
    bn_stats_kernel<<<512, 256, 0, stream>>>(xb, stats);

    // 8. out = h + relu(BN(y2))
    bn_final_kernel<<<1024, 256, 0, stream>>>(xb, h, gamma, beta, stats, out);
}